// Round 3
// baseline (509.020 us; speedup 1.0000x reference)
//
#include <hip/hip_runtime.h>
#include <math.h>

#define HN       250
#define WN       400
#define N_RAYS   (HN * WN)        // 100000
#define N_SAMP   1000000
#define P_TENSO  50000
#define C_CH     16
#define DIMV     8
#define STEP_SZ  0.005f
#define DENS_SCALE 1.0f           // min(1/(1-0), 25) = 1

// ---------------- workspace layout (bytes) ----------------
// sdata   : 1M x 32B  reordered sample structs          [0, 32e6)
// results : 1M x 16B  per-sample (lt, r, g, b)          [32e6, 48e6)
// counts  : 50K int                                      [48.0e6, 48.2e6)
// starts  : 50K int   exclusive scan of counts           [48.2e6, 48.4e6)
// cursor  : 50K int   scatter cursors                    [48.4e6, 48.6e6)
// bsums   : 256 int                                      [48.6e6, ...)
#define OFF_SDATA   0
#define OFF_RESULTS 32000000
#define OFF_COUNTS  48000000
#define OFF_STARTS  48200000
#define OFF_CURSOR  48400000
#define OFF_BSUMS   48600000
#define WS_NEED     (48600000 + 1024)

__global__ __launch_bounds__(256) void zero_ints(int* p, int n) {
    int i = blockIdx.x * 256 + threadIdx.x;
    if (i < n) p[i] = 0;
}

__global__ __launch_bounds__(256) void hist_tid(const int* __restrict__ tenso_id,
                                                int* __restrict__ counts) {
    int n = blockIdx.x * 256 + threadIdx.x;
    if (n < N_SAMP) atomicAdd(&counts[tenso_id[n]], 1);
}

// block scans 1024 elements (4/thread), writes exclusive scan + block total
__global__ __launch_bounds__(256) void scan_local(const int* __restrict__ in,
                                                  int* __restrict__ out,
                                                  int* __restrict__ bsums, int n) {
    __shared__ int lds[256];
    const int t = threadIdx.x;
    const int base = blockIdx.x * 1024;
    int v[4]; int s = 0;
    #pragma unroll
    for (int i = 0; i < 4; ++i) {
        int idx = base + t * 4 + i;
        v[i] = (idx < n) ? in[idx] : 0;
        s += v[i];
    }
    lds[t] = s;
    __syncthreads();
    for (int d = 1; d < 256; d <<= 1) {
        int x = (t >= d) ? lds[t - d] : 0;
        __syncthreads();
        lds[t] += x;
        __syncthreads();
    }
    int run = (t > 0) ? lds[t - 1] : 0;
    #pragma unroll
    for (int i = 0; i < 4; ++i) {
        int idx = base + t * 4 + i;
        if (idx < n) out[idx] = run;
        run += v[i];
    }
    if (t == 255) bsums[blockIdx.x] = lds[255];
}

// single wave scans the <=64 block totals (exclusive, in place)
__global__ __launch_bounds__(64) void scan_totals(int* __restrict__ bsums, int nb) {
    int t = threadIdx.x;
    int v = (t < nb) ? bsums[t] : 0;
    #pragma unroll
    for (int d = 1; d < 64; d <<= 1) {
        int u = __shfl_up(v, d, 64);
        if (t >= d) v += u;
    }
    int excl = __shfl_up(v, 1, 64);
    if (t == 0) excl = 0;
    if (t < nb) bsums[t] = excl;
}

__global__ __launch_bounds__(256) void scan_add(int* __restrict__ out,
                                                const int* __restrict__ bsums, int n) {
    int i = blockIdx.x * 256 + threadIdx.x;
    if (i < n) out[i] += bsums[i >> 10];
}

// scatter: reorder per-sample data into tid-grouped order.
// struct (32B): {ws0,ws1,ws2,wl0} {wl1,wl2, bits(idxpack), bits(orig_n)}
__global__ __launch_bounds__(256) void scatter_samples(
    const int*   __restrict__ tenso_id,
    const int*   __restrict__ gis, const int* __restrict__ gil,
    const float* __restrict__ gws, const float* __restrict__ gwl,
    const int*   __restrict__ starts, int* __restrict__ cursor,
    float4* __restrict__ sdata)
{
    int n = blockIdx.x * 256 + threadIdx.x;
    if (n >= N_SAMP) return;
    int tid = tenso_id[n];
    int pos = starts[tid] + atomicAdd(&cursor[tid], 1);
    unsigned bits = (unsigned)gis[n*3+0] | ((unsigned)gis[n*3+1] << 3) | ((unsigned)gis[n*3+2] << 6)
                  | ((unsigned)gil[n*3+0] << 9) | ((unsigned)gil[n*3+1] << 12) | ((unsigned)gil[n*3+2] << 15);
    float4 A = make_float4(gws[n*3+0], gws[n*3+1], gws[n*3+2], gwl[n*3+0]);
    float4 B = make_float4(gwl[n*3+1], gwl[n*3+2], __uint_as_float(bits), __uint_as_float((unsigned)n));
    sdata[(size_t)pos * 2 + 0] = A;
    sdata[(size_t)pos * 2 + 1] = B;
}

// ---------------------------------------------------------------------------
// Gather phase: one wave per tensoRF id. Slab staged to LDS once (transposed,
// pad stride 17 to spread banks), then lanes = 4 samples x 16 channels.
// Emits per-sample (lt, sigmoid(rgb)) to results[orig_n].
// ---------------------------------------------------------------------------
#define TV_LDS   408   // 3*136, stride 17 per dim-row of 16 channels
#define SLAB_F   480   // 408 tv + 16 dens + 48 col + 8 pad
__global__ __launch_bounds__(256) void gather_phase(
    const float* __restrict__ trivecs,   // (P,16,3,8)
    const float* __restrict__ densities, // (P,16)
    const float* __restrict__ colors,    // (P,16,3)
    const int*   __restrict__ starts,
    const int*   __restrict__ counts,
    const float4* __restrict__ sdata,
    float4* __restrict__ results)
{
    __shared__ float lds[4 * SLAB_F];
    const int lane = threadIdx.x & 63;
    const int wv   = threadIdx.x >> 6;
    const int t    = blockIdx.x * 4 + wv;
    if (t >= P_TENSO) return;

    const int start = starts[t];
    const int cnt   = counts[t];
    if (cnt == 0) return;

    float* slab = lds + wv * SLAB_F;
    float* dl   = slab + TV_LDS;        // 16 densities
    float* cl   = dl + 16;              // 48 colors (3,16)

    // stage trivec slab, transposing (c,a,d) -> [a*136 + d*17 + c]
    const float* tvg = trivecs + (size_t)t * 384;
    #pragma unroll
    for (int i = 0; i < 6; ++i) {
        int l = lane + i * 64;          // 0..383, coalesced global read
        int c = l / 24;
        int rem = l - c * 24;
        int a = rem >> 3;
        int d = rem & 7;
        slab[a * 136 + d * 17 + c] = tvg[l];
    }
    if (lane < 16) dl[lane] = densities[(size_t)t * 16 + lane];
    if (lane < 48) {
        int c = lane / 3, k = lane - c * 3;
        cl[k * 16 + c] = colors[(size_t)t * 48 + lane];
    }
    // same-wave LDS write->read dependency: compiler inserts lgkmcnt wait

    const int c = lane & 15;
    const int g = lane >> 4;
    const int end = start + cnt;
    const int niter = (cnt + 3) >> 2;

    for (int it = 0; it < niter; ++it) {
        const int pos = start + it * 4 + g;
        const bool valid = (pos < end);
        const int cp = valid ? pos : (end - 1);
        float4 A = sdata[(size_t)cp * 2 + 0];
        float4 B = sdata[(size_t)cp * 2 + 1];
        const unsigned bits = __float_as_uint(B.z);
        const unsigned orig = __float_as_uint(B.w);

        float f;
        {
            int is = bits & 7,        il = (bits >> 9) & 7;
            f  = slab[is * 17 + c] * A.x + slab[il * 17 + c] * A.w;
        }
        {
            int is = (bits >> 3) & 7, il = (bits >> 12) & 7;
            f *= slab[136 + is * 17 + c] * A.y + slab[136 + il * 17 + c] * B.x;
        }
        {
            int is = (bits >> 6) & 7, il = (bits >> 15) & 7;
            f *= slab[272 + is * 17 + c] * A.z + slab[272 + il * 17 + c] * B.y;
        }

        float s0 = f * dl[c];
        float s1 = f * cl[c];
        float s2 = f * cl[16 + c];
        float s3 = f * cl[32 + c];

        #pragma unroll
        for (int m = 1; m < 16; m <<= 1) {
            s0 += __shfl_xor(s0, m);
            s1 += __shfl_xor(s1, m);
            s2 += __shfl_xor(s2, m);
            s3 += __shfl_xor(s3, m);
        }

        const float sigma = s0;
        float dens = fmaxf(sigma, 0.0f) + __logf(1.0f + __expf(-fabsf(sigma)));
        dens *= DENS_SCALE;
        const float lt = -dens * STEP_SZ;
        const float rr = 1.0f / (1.0f + __expf(-s1));
        const float gg = 1.0f / (1.0f + __expf(-s2));
        const float bb = 1.0f / (1.0f + __expf(-s3));

        if (valid && c == 0) results[orig] = make_float4(lt, rr, gg, bb);
    }
}

// ---------------------------------------------------------------------------
// Scan phase: one wave per ray; 64 samples/iter; shfl inclusive scan of lt.
// ---------------------------------------------------------------------------
__global__ __launch_bounds__(256) void scan_phase(
    const float4* __restrict__ results,
    const float*  __restrict__ t_min,
    const float*  __restrict__ bg,
    const int*    __restrict__ ray_id,   // sorted
    const int*    __restrict__ step_id,
    float* __restrict__ out)
{
    const int lane = threadIdx.x & 63;
    const int r = blockIdx.x * 4 + (threadIdx.x >> 6);
    if (r >= N_RAYS) return;

    // wave-uniform binary searches
    int lo = 0, hi = N_SAMP;
    while (lo < hi) { int mid = (lo + hi) >> 1; if (ray_id[mid] < r) lo = mid + 1; else hi = mid; }
    const int seg_start = lo;
    hi = N_SAMP;
    while (lo < hi) { int mid = (lo + hi) >> 1; if (ray_id[mid] < r + 1) lo = mid + 1; else hi = mid; }
    const int seg_end = lo;

    const float tmin_r = t_min[r];
    float Tlog = 0.0f;
    float accR = 0.0f, accG = 0.0f, accB = 0.0f, accD = 0.0f;

    for (int base = seg_start; base < seg_end; base += 64) {
        const int n = base + lane;
        const bool valid = (n < seg_end);
        const int nn = valid ? n : (seg_end - 1);
        float4 res;
        float lt;
        if (valid) { res = results[n]; lt = res.x; }
        else       { res = make_float4(0.f, 0.f, 0.f, 0.f); lt = 0.0f; }

        float incl = lt;
        #pragma unroll
        for (int d = 1; d < 64; d <<= 1) {
            float u = __shfl_up(incl, d, 64);
            if (lane >= d) incl += u;
        }
        const float excl = Tlog + incl - lt;
        const float alpha = 1.0f - __expf(lt);
        const float w = valid ? alpha * __expf(excl) : 0.0f;
        const float z = tmin_r + (float)step_id[nn] * STEP_SZ;

        accR += w * res.y;
        accG += w * res.z;
        accB += w * res.w;
        accD += w * z;

        Tlog += __shfl(incl, 63, 64);
    }

    #pragma unroll
    for (int m = 1; m < 64; m <<= 1) {
        accR += __shfl_xor(accR, m);
        accG += __shfl_xor(accG, m);
        accB += __shfl_xor(accB, m);
        accD += __shfl_xor(accD, m);
    }

    const float bgw = __expf(Tlog);
    if (lane == 0) {
        out[0 * N_RAYS + r] = accR + bgw * bg[0];
        out[1 * N_RAYS + r] = accG + bgw * bg[1];
        out[2 * N_RAYS + r] = accB + bgw * bg[2];
        out[3 * N_RAYS + r] = accD;
        out[4 * N_RAYS + r] = 1.0f - bgw;
    }
}

// ---------------------------------------------------------------------------
// Fallback (ws too small): R2's single fused kernel, original layouts.
// ---------------------------------------------------------------------------
__global__ __launch_bounds__(256) void trivec_render_fallback(
    const float* __restrict__ trivecs, const float* __restrict__ densities,
    const float* __restrict__ colors, const float* __restrict__ gws,
    const float* __restrict__ gwl, const float* __restrict__ t_min,
    const float* __restrict__ bg, const int* __restrict__ gis,
    const int* __restrict__ gil, const int* __restrict__ tenso_id,
    const int* __restrict__ ray_id, const int* __restrict__ step_id,
    float* __restrict__ out)
{
    const int lane = threadIdx.x & 63;
    const int r = blockIdx.x * 4 + (threadIdx.x >> 6);
    if (r >= N_RAYS) return;
    const int c = lane & 15;
    const int g = lane >> 4;
    int lo = 0, hi = N_SAMP;
    while (lo < hi) { int mid = (lo + hi) >> 1; if (ray_id[mid] < r) lo = mid + 1; else hi = mid; }
    const int seg_start = lo;
    hi = N_SAMP;
    while (lo < hi) { int mid = (lo + hi) >> 1; if (ray_id[mid] < r + 1) lo = mid + 1; else hi = mid; }
    const int seg_end = lo;
    const float tmin_r = t_min[r];
    float Tlog = 0.0f, accR = 0.0f, accG = 0.0f, accB = 0.0f, accD = 0.0f;
    const int niter = (seg_end - seg_start + 3) >> 2;
    for (int it = 0; it < niter; ++it) {
        const int n = seg_start + it * 4 + g;
        const bool valid = (n < seg_end);
        const int nc = valid ? n : (seg_end - 1);
        const int tid = tenso_id[nc];
        const float* tv = trivecs + (size_t)tid * 384 + c * 24;
        float f = 1.0f;
        #pragma unroll
        for (int a = 0; a < 3; ++a) {
            const int is = gis[nc*3+a], il = gil[nc*3+a];
            const float wS = gws[nc*3+a], wL = gwl[nc*3+a];
            f *= (tv[a*8+is] * wS + tv[a*8+il] * wL);
        }
        const float dns = densities[(size_t)tid * 16 + c];
        const float* colp = colors + ((size_t)tid * 16 + c) * 3;
        float s0 = f*dns, s1 = f*colp[0], s2 = f*colp[1], s3 = f*colp[2];
        #pragma unroll
        for (int m = 1; m < 16; m <<= 1) {
            s0 += __shfl_xor(s0, m); s1 += __shfl_xor(s1, m);
            s2 += __shfl_xor(s2, m); s3 += __shfl_xor(s3, m);
        }
        float dens = fmaxf(s0, 0.0f) + __logf(1.0f + __expf(-fabsf(s0)));
        const float lt = valid ? (-dens * STEP_SZ) : 0.0f;
        const float alpha = 1.0f - __expf(lt);
        const float rr = 1.0f/(1.0f+__expf(-s1)), gg = 1.0f/(1.0f+__expf(-s2)), bb = 1.0f/(1.0f+__expf(-s3));
        const float z = tmin_r + (float)step_id[nc] * STEP_SZ;
        const float lt0 = __shfl(lt,0), lt1 = __shfl(lt,16), lt2 = __shfl(lt,32), lt3 = __shfl(lt,48);
        float excl = Tlog;
        if (g > 0) excl += lt0;
        if (g > 1) excl += lt1;
        if (g > 2) excl += lt2;
        const float w = alpha * __expf(excl);
        Tlog += lt0 + lt1 + lt2 + lt3;
        accR += w*rr; accG += w*gg; accB += w*bb; accD += w*z;
    }
    accR += __shfl_xor(accR,16); accR += __shfl_xor(accR,32);
    accG += __shfl_xor(accG,16); accG += __shfl_xor(accG,32);
    accB += __shfl_xor(accB,16); accB += __shfl_xor(accB,32);
    accD += __shfl_xor(accD,16); accD += __shfl_xor(accD,32);
    const float bgw = __expf(Tlog);
    if (lane == 0) {
        out[0*N_RAYS+r] = accR + bgw*bg[0];
        out[1*N_RAYS+r] = accG + bgw*bg[1];
        out[2*N_RAYS+r] = accB + bgw*bg[2];
        out[3*N_RAYS+r] = accD;
        out[4*N_RAYS+r] = 1.0f - bgw;
    }
}

extern "C" void kernel_launch(void* const* d_in, const int* in_sizes, int n_in,
                              void* d_out, int out_size, void* d_ws, size_t ws_size,
                              hipStream_t stream) {
    const float* trivecs   = (const float*)d_in[0];
    const float* densities = (const float*)d_in[1];
    const float* colors    = (const float*)d_in[2];
    const float* gws       = (const float*)d_in[3];
    const float* gwl       = (const float*)d_in[4];
    const float* t_min     = (const float*)d_in[5];
    const float* bg        = (const float*)d_in[6];
    const int*   gis       = (const int*)d_in[7];
    const int*   gil       = (const int*)d_in[8];
    const int*   tenso_id  = (const int*)d_in[9];
    const int*   ray_id    = (const int*)d_in[10];
    const int*   step_id   = (const int*)d_in[11];
    float* out = (float*)d_out;

    if (ws_size < (size_t)WS_NEED) {
        trivec_render_fallback<<<(N_RAYS + 3) / 4, 256, 0, stream>>>(
            trivecs, densities, colors, gws, gwl, t_min, bg,
            gis, gil, tenso_id, ray_id, step_id, out);
        return;
    }

    char* ws = (char*)d_ws;
    float4* sdata   = (float4*)(ws + OFF_SDATA);
    float4* results = (float4*)(ws + OFF_RESULTS);
    int*    counts  = (int*)(ws + OFF_COUNTS);
    int*    starts  = (int*)(ws + OFF_STARTS);
    int*    cursor  = (int*)(ws + OFF_CURSOR);
    int*    bsums   = (int*)(ws + OFF_BSUMS);

    const int NB = (P_TENSO + 1023) / 1024;   // 49

    // zero counts+starts+cursor region (150K ints, contiguous)
    zero_ints<<<(150000 + 255) / 256, 256, 0, stream>>>(counts, 150000);
    hist_tid<<<(N_SAMP + 255) / 256, 256, 0, stream>>>(tenso_id, counts);
    scan_local<<<NB, 256, 0, stream>>>(counts, starts, bsums, P_TENSO);
    scan_totals<<<1, 64, 0, stream>>>(bsums, NB);
    scan_add<<<(P_TENSO + 255) / 256, 256, 0, stream>>>(starts, bsums, P_TENSO);
    scatter_samples<<<(N_SAMP + 255) / 256, 256, 0, stream>>>(
        tenso_id, gis, gil, gws, gwl, starts, cursor, sdata);
    gather_phase<<<(P_TENSO + 3) / 4, 256, 0, stream>>>(
        trivecs, densities, colors, starts, counts, sdata, results);
    scan_phase<<<(N_RAYS + 3) / 4, 256, 0, stream>>>(
        results, t_min, bg, ray_id, step_id, out);
}

// Round 4
// 362.097 us; speedup vs baseline: 1.4058x; 1.4058x over previous
//
#include <hip/hip_runtime.h>
#include <math.h>

#define HN       250
#define WN       400
#define N_RAYS   (HN * WN)        // 100000
#define N_SAMP   1000000
#define P_TENSO  50000
#define C_CH     16
#define DIMV     8
#define STEP_SZ  0.005f
#define DENS_SCALE 1.0f           // min(1/(1-0), 25) = 1

// ---------------- workspace layout (bytes) ----------------
#define OFF_SDATA   0            // 1M x 32B reordered sample structs
#define OFF_RESULTS 32000000     // 1M x 16B per-sample (lt, r, g, b)
#define OFF_COUNTS  48000000     // 50K int
#define OFF_STARTS  48200000     // 50K int
#define OFF_CURSOR  48400000     // 50K int
#define OFF_BSUMS   48600000     // 256 int
#define OFF_RSTART  48601024     // (N_RAYS+1) int = 400004 B
#define WS_NEED     (48601024 + 400004 + 64)

__global__ __launch_bounds__(256) void zero_ints(int* p, int n) {
    int i = blockIdx.x * 256 + threadIdx.x;
    if (i < n) p[i] = 0;
}

__global__ __launch_bounds__(256) void hist_tid(const int* __restrict__ tenso_id,
                                                int* __restrict__ counts) {
    int n = blockIdx.x * 256 + threadIdx.x;
    if (n < N_SAMP) atomicAdd(&counts[tenso_id[n]], 1);
}

// block scans 1024 elements (4/thread), writes exclusive scan + block total
__global__ __launch_bounds__(256) void scan_local(const int* __restrict__ in,
                                                  int* __restrict__ out,
                                                  int* __restrict__ bsums, int n) {
    __shared__ int lds[256];
    const int t = threadIdx.x;
    const int base = blockIdx.x * 1024;
    int v[4]; int s = 0;
    #pragma unroll
    for (int i = 0; i < 4; ++i) {
        int idx = base + t * 4 + i;
        v[i] = (idx < n) ? in[idx] : 0;
        s += v[i];
    }
    lds[t] = s;
    __syncthreads();
    for (int d = 1; d < 256; d <<= 1) {
        int x = (t >= d) ? lds[t - d] : 0;
        __syncthreads();
        lds[t] += x;
        __syncthreads();
    }
    int run = (t > 0) ? lds[t - 1] : 0;
    #pragma unroll
    for (int i = 0; i < 4; ++i) {
        int idx = base + t * 4 + i;
        if (idx < n) out[idx] = run;
        run += v[i];
    }
    if (t == 255) bsums[blockIdx.x] = lds[255];
}

// single wave scans the <=64 block totals (exclusive, in place)
__global__ __launch_bounds__(64) void scan_totals(int* __restrict__ bsums, int nb) {
    int t = threadIdx.x;
    int v = (t < nb) ? bsums[t] : 0;
    #pragma unroll
    for (int d = 1; d < 64; d <<= 1) {
        int u = __shfl_up(v, d, 64);
        if (t >= d) v += u;
    }
    int excl = __shfl_up(v, 1, 64);
    if (t == 0) excl = 0;
    if (t < nb) bsums[t] = excl;
}

// finalize starts and initialize scatter cursors in one pass
__global__ __launch_bounds__(256) void scan_add(int* __restrict__ starts,
                                                int* __restrict__ cursor,
                                                const int* __restrict__ bsums, int n) {
    int i = blockIdx.x * 256 + threadIdx.x;
    if (i < n) { int v = starts[i] + bsums[i >> 10]; starts[i] = v; cursor[i] = v; }
}

// ray segment boundaries: ray_start[r] = first n with ray_id[n] >= r
__global__ __launch_bounds__(256) void ray_starts_kernel(const int* __restrict__ ray_id,
                                                         int* __restrict__ ray_start) {
    int n = blockIdx.x * 256 + threadIdx.x;
    if (n >= N_SAMP) return;
    int r = ray_id[n];
    int rprev = (n == 0) ? -1 : ray_id[n - 1];
    for (int q = rprev + 1; q <= r; ++q) ray_start[q] = n;
    if (n == N_SAMP - 1) {
        for (int q = r + 1; q <= N_RAYS; ++q) ray_start[q] = N_SAMP;
    }
}

// scatter: reorder per-sample data into tid-grouped order.
// struct (32B): {ws0,ws1,ws2,wl0} {wl1,wl2, bits(idxpack), bits(orig_n)}
__global__ __launch_bounds__(256) void scatter_samples(
    const int*   __restrict__ tenso_id,
    const int*   __restrict__ gis, const int* __restrict__ gil,
    const float* __restrict__ gws, const float* __restrict__ gwl,
    int* __restrict__ cursor,
    float4* __restrict__ sdata)
{
    int n = blockIdx.x * 256 + threadIdx.x;
    if (n >= N_SAMP) return;
    int tid = tenso_id[n];
    int pos = atomicAdd(&cursor[tid], 1);
    unsigned bits = (unsigned)gis[n*3+0] | ((unsigned)gis[n*3+1] << 3) | ((unsigned)gis[n*3+2] << 6)
                  | ((unsigned)gil[n*3+0] << 9) | ((unsigned)gil[n*3+1] << 12) | ((unsigned)gil[n*3+2] << 15);
    float4 A = make_float4(gws[n*3+0], gws[n*3+1], gws[n*3+2], gwl[n*3+0]);
    float4 B = make_float4(gwl[n*3+1], gwl[n*3+2], __uint_as_float(bits), __uint_as_float((unsigned)n));
    sdata[(size_t)pos * 2 + 0] = A;
    sdata[(size_t)pos * 2 + 1] = B;
}

// ---------------------------------------------------------------------------
// Gather phase: one wave per tensoRF id. Slab staged to LDS once (transposed,
// pad stride 17), lanes = 4 samples x 16 channels. Emits (lt, rgb) per sample.
// ---------------------------------------------------------------------------
#define TV_LDS   408   // 3*136
#define SLAB_F   480   // 408 tv + 16 dens + 48 col + 8 pad
__global__ __launch_bounds__(256) void gather_phase(
    const float* __restrict__ trivecs,   // (P,16,3,8)
    const float* __restrict__ densities, // (P,16)
    const float* __restrict__ colors,    // (P,16,3)
    const int*   __restrict__ starts,
    const int*   __restrict__ counts,
    const float4* __restrict__ sdata,
    float4* __restrict__ results)
{
    __shared__ float lds[4 * SLAB_F];
    const int lane = threadIdx.x & 63;
    const int wv   = threadIdx.x >> 6;
    const int t    = blockIdx.x * 4 + wv;
    if (t >= P_TENSO) return;

    const int start = starts[t];
    const int cnt   = counts[t];
    if (cnt == 0) return;

    float* slab = lds + wv * SLAB_F;
    float* dl   = slab + TV_LDS;
    float* cl   = dl + 16;

    const float* tvg = trivecs + (size_t)t * 384;
    #pragma unroll
    for (int i = 0; i < 6; ++i) {
        int l = lane + i * 64;
        int c = l / 24;
        int rem = l - c * 24;
        int a = rem >> 3;
        int d = rem & 7;
        slab[a * 136 + d * 17 + c] = tvg[l];
    }
    if (lane < 16) dl[lane] = densities[(size_t)t * 16 + lane];
    if (lane < 48) {
        int c = lane / 3, k = lane - c * 3;
        cl[k * 16 + c] = colors[(size_t)t * 48 + lane];
    }

    const int c = lane & 15;
    const int g = lane >> 4;
    const int end = start + cnt;
    const int niter = (cnt + 3) >> 2;

    for (int it = 0; it < niter; ++it) {
        const int pos = start + it * 4 + g;
        const bool valid = (pos < end);
        const int cp = valid ? pos : (end - 1);
        float4 A = sdata[(size_t)cp * 2 + 0];
        float4 B = sdata[(size_t)cp * 2 + 1];
        const unsigned bits = __float_as_uint(B.z);
        const unsigned orig = __float_as_uint(B.w);

        float f;
        {
            int is = bits & 7,        il = (bits >> 9) & 7;
            f  = slab[is * 17 + c] * A.x + slab[il * 17 + c] * A.w;
        }
        {
            int is = (bits >> 3) & 7, il = (bits >> 12) & 7;
            f *= slab[136 + is * 17 + c] * A.y + slab[136 + il * 17 + c] * B.x;
        }
        {
            int is = (bits >> 6) & 7, il = (bits >> 15) & 7;
            f *= slab[272 + is * 17 + c] * A.z + slab[272 + il * 17 + c] * B.y;
        }

        float s0 = f * dl[c];
        float s1 = f * cl[c];
        float s2 = f * cl[16 + c];
        float s3 = f * cl[32 + c];

        #pragma unroll
        for (int m = 1; m < 16; m <<= 1) {
            s0 += __shfl_xor(s0, m);
            s1 += __shfl_xor(s1, m);
            s2 += __shfl_xor(s2, m);
            s3 += __shfl_xor(s3, m);
        }

        float dens = fmaxf(s0, 0.0f) + __logf(1.0f + __expf(-fabsf(s0)));
        dens *= DENS_SCALE;
        const float lt = -dens * STEP_SZ;
        const float rr = 1.0f / (1.0f + __expf(-s1));
        const float gg = 1.0f / (1.0f + __expf(-s2));
        const float bb = 1.0f / (1.0f + __expf(-s3));

        if (valid && c == 0) results[orig] = make_float4(lt, rr, gg, bb);
    }
}

// ---------------------------------------------------------------------------
// Final pass: ONE THREAD PER RAY (avg 10 samples). Sequential transmittance
// recurrence in-register; no shuffles, no binary search (ray_start array).
// ---------------------------------------------------------------------------
__global__ __launch_bounds__(256) void ray_render(
    const float4* __restrict__ results,
    const float*  __restrict__ t_min,
    const float*  __restrict__ bg,
    const int*    __restrict__ ray_start,
    const int*    __restrict__ step_id,
    float* __restrict__ out)
{
    int r = blockIdx.x * 256 + threadIdx.x;
    if (r >= N_RAYS) return;
    const int s = ray_start[r];
    const int e = ray_start[r + 1];
    const float tmin_r = t_min[r];

    float T = 0.0f, aR = 0.0f, aG = 0.0f, aB = 0.0f, aD = 0.0f;
    for (int n = s; n < e; ++n) {
        float4 res = results[n];
        const float lt = res.x;
        const float w = (1.0f - __expf(lt)) * __expf(T);   // alpha * exp(excl)
        T += lt;
        const float z = tmin_r + (float)step_id[n] * STEP_SZ;
        aR += w * res.y;
        aG += w * res.z;
        aB += w * res.w;
        aD += w * z;
    }
    const float bgw = __expf(T);
    out[0 * N_RAYS + r] = aR + bgw * bg[0];
    out[1 * N_RAYS + r] = aG + bgw * bg[1];
    out[2 * N_RAYS + r] = aB + bgw * bg[2];
    out[3 * N_RAYS + r] = aD;
    out[4 * N_RAYS + r] = 1.0f - bgw;
}

// ---------------------------------------------------------------------------
// Fallback (ws too small): single fused kernel, original layouts.
// ---------------------------------------------------------------------------
__global__ __launch_bounds__(256) void trivec_render_fallback(
    const float* __restrict__ trivecs, const float* __restrict__ densities,
    const float* __restrict__ colors, const float* __restrict__ gws,
    const float* __restrict__ gwl, const float* __restrict__ t_min,
    const float* __restrict__ bg, const int* __restrict__ gis,
    const int* __restrict__ gil, const int* __restrict__ tenso_id,
    const int* __restrict__ ray_id, const int* __restrict__ step_id,
    float* __restrict__ out)
{
    const int lane = threadIdx.x & 63;
    const int r = blockIdx.x * 4 + (threadIdx.x >> 6);
    if (r >= N_RAYS) return;
    const int c = lane & 15;
    const int g = lane >> 4;
    int lo = 0, hi = N_SAMP;
    while (lo < hi) { int mid = (lo + hi) >> 1; if (ray_id[mid] < r) lo = mid + 1; else hi = mid; }
    const int seg_start = lo;
    hi = N_SAMP;
    while (lo < hi) { int mid = (lo + hi) >> 1; if (ray_id[mid] < r + 1) lo = mid + 1; else hi = mid; }
    const int seg_end = lo;
    const float tmin_r = t_min[r];
    float Tlog = 0.0f, accR = 0.0f, accG = 0.0f, accB = 0.0f, accD = 0.0f;
    const int niter = (seg_end - seg_start + 3) >> 2;
    for (int it = 0; it < niter; ++it) {
        const int n = seg_start + it * 4 + g;
        const bool valid = (n < seg_end);
        const int nc = valid ? n : (seg_end - 1);
        const int tid = tenso_id[nc];
        const float* tv = trivecs + (size_t)tid * 384 + c * 24;
        float f = 1.0f;
        #pragma unroll
        for (int a = 0; a < 3; ++a) {
            const int is = gis[nc*3+a], il = gil[nc*3+a];
            const float wS = gws[nc*3+a], wL = gwl[nc*3+a];
            f *= (tv[a*8+is] * wS + tv[a*8+il] * wL);
        }
        const float dns = densities[(size_t)tid * 16 + c];
        const float* colp = colors + ((size_t)tid * 16 + c) * 3;
        float s0 = f*dns, s1 = f*colp[0], s2 = f*colp[1], s3 = f*colp[2];
        #pragma unroll
        for (int m = 1; m < 16; m <<= 1) {
            s0 += __shfl_xor(s0, m); s1 += __shfl_xor(s1, m);
            s2 += __shfl_xor(s2, m); s3 += __shfl_xor(s3, m);
        }
        float dens = fmaxf(s0, 0.0f) + __logf(1.0f + __expf(-fabsf(s0)));
        const float lt = valid ? (-dens * STEP_SZ) : 0.0f;
        const float alpha = 1.0f - __expf(lt);
        const float rr = 1.0f/(1.0f+__expf(-s1)), gg = 1.0f/(1.0f+__expf(-s2)), bb = 1.0f/(1.0f+__expf(-s3));
        const float z = tmin_r + (float)step_id[nc] * STEP_SZ;
        const float lt0 = __shfl(lt,0), lt1 = __shfl(lt,16), lt2 = __shfl(lt,32), lt3 = __shfl(lt,48);
        float excl = Tlog;
        if (g > 0) excl += lt0;
        if (g > 1) excl += lt1;
        if (g > 2) excl += lt2;
        const float w = alpha * __expf(excl);
        Tlog += lt0 + lt1 + lt2 + lt3;
        accR += w*rr; accG += w*gg; accB += w*bb; accD += w*z;
    }
    accR += __shfl_xor(accR,16); accR += __shfl_xor(accR,32);
    accG += __shfl_xor(accG,16); accG += __shfl_xor(accG,32);
    accB += __shfl_xor(accB,16); accB += __shfl_xor(accB,32);
    accD += __shfl_xor(accD,16); accD += __shfl_xor(accD,32);
    const float bgw = __expf(Tlog);
    if (lane == 0) {
        out[0*N_RAYS+r] = accR + bgw*bg[0];
        out[1*N_RAYS+r] = accG + bgw*bg[1];
        out[2*N_RAYS+r] = accB + bgw*bg[2];
        out[3*N_RAYS+r] = accD;
        out[4*N_RAYS+r] = 1.0f - bgw;
    }
}

extern "C" void kernel_launch(void* const* d_in, const int* in_sizes, int n_in,
                              void* d_out, int out_size, void* d_ws, size_t ws_size,
                              hipStream_t stream) {
    const float* trivecs   = (const float*)d_in[0];
    const float* densities = (const float*)d_in[1];
    const float* colors    = (const float*)d_in[2];
    const float* gws       = (const float*)d_in[3];
    const float* gwl       = (const float*)d_in[4];
    const float* t_min     = (const float*)d_in[5];
    const float* bg        = (const float*)d_in[6];
    const int*   gis       = (const int*)d_in[7];
    const int*   gil       = (const int*)d_in[8];
    const int*   tenso_id  = (const int*)d_in[9];
    const int*   ray_id    = (const int*)d_in[10];
    const int*   step_id   = (const int*)d_in[11];
    float* out = (float*)d_out;

    if (ws_size < (size_t)WS_NEED) {
        trivec_render_fallback<<<(N_RAYS + 3) / 4, 256, 0, stream>>>(
            trivecs, densities, colors, gws, gwl, t_min, bg,
            gis, gil, tenso_id, ray_id, step_id, out);
        return;
    }

    char* ws = (char*)d_ws;
    float4* sdata    = (float4*)(ws + OFF_SDATA);
    float4* results  = (float4*)(ws + OFF_RESULTS);
    int*    counts   = (int*)(ws + OFF_COUNTS);
    int*    starts   = (int*)(ws + OFF_STARTS);
    int*    cursor   = (int*)(ws + OFF_CURSOR);
    int*    bsums    = (int*)(ws + OFF_BSUMS);
    int*    raystart = (int*)(ws + OFF_RSTART);

    const int NB = (P_TENSO + 1023) / 1024;   // 49

    zero_ints<<<(P_TENSO + 255) / 256, 256, 0, stream>>>(counts, P_TENSO);
    hist_tid<<<(N_SAMP + 255) / 256, 256, 0, stream>>>(tenso_id, counts);
    scan_local<<<NB, 256, 0, stream>>>(counts, starts, bsums, P_TENSO);
    scan_totals<<<1, 64, 0, stream>>>(bsums, NB);
    scan_add<<<(P_TENSO + 255) / 256, 256, 0, stream>>>(starts, cursor, bsums, P_TENSO);
    ray_starts_kernel<<<(N_SAMP + 255) / 256, 256, 0, stream>>>(ray_id, raystart);
    scatter_samples<<<(N_SAMP + 255) / 256, 256, 0, stream>>>(
        tenso_id, gis, gil, gws, gwl, cursor, sdata);
    gather_phase<<<(P_TENSO + 3) / 4, 256, 0, stream>>>(
        trivecs, densities, colors, starts, counts, sdata, results);
    ray_render<<<(N_RAYS + 255) / 256, 256, 0, stream>>>(
        results, t_min, bg, raystart, step_id, out);
}

// Round 5
// 313.657 us; speedup vs baseline: 1.6229x; 1.1544x over previous
//
#include <hip/hip_runtime.h>
#include <math.h>

#define HN       250
#define WN       400
#define N_RAYS   (HN * WN)        // 100000
#define N_SAMP   1000000
#define P_TENSO  50000
#define C_CH     16
#define DIMV     8
#define STEP_SZ  0.005f
#define DENS_SCALE 1.0f           // min(1/(1-0), 25) = 1

// ---------------- workspace layout (bytes) ----------------
#define OFF_SDATA   0            // 1M x 32B reordered sample structs
#define OFF_RESULTS 32000000     // 1M x 16B per-sample (lt, r, g, b)
#define OFF_COUNTS  48000000     // 50K int
#define OFF_STARTS  48200000     // 50K int
#define OFF_CURSOR  48400000     // 50K int
#define OFF_BSUMS   48600000     // 256 int
#define OFF_RSTART  48601024     // (N_RAYS+1) int
#define WS_NEED     (48601024 + 400004 + 64)

__global__ __launch_bounds__(256) void zero_ints(int* p, int n) {
    int i = blockIdx.x * 256 + threadIdx.x;
    if (i < n) p[i] = 0;
}

// fused: tid histogram + ray segment boundaries (ray_id sorted)
__global__ __launch_bounds__(256) void hist_and_bounds(
    const int* __restrict__ tenso_id, const int* __restrict__ ray_id,
    int* __restrict__ counts, int* __restrict__ ray_start) {
    int n = blockIdx.x * 256 + threadIdx.x;
    if (n >= N_SAMP) return;
    atomicAdd(&counts[tenso_id[n]], 1);
    int r = ray_id[n];
    int rprev = (n == 0) ? -1 : ray_id[n - 1];
    for (int q = rprev + 1; q <= r; ++q) ray_start[q] = n;
    if (n == N_SAMP - 1) {
        for (int q = r + 1; q <= N_RAYS; ++q) ray_start[q] = N_SAMP;
    }
}

// block scans 1024 elements (4/thread), writes exclusive scan + block total
__global__ __launch_bounds__(256) void scan_local(const int* __restrict__ in,
                                                  int* __restrict__ out,
                                                  int* __restrict__ bsums, int n) {
    __shared__ int lds[256];
    const int t = threadIdx.x;
    const int base = blockIdx.x * 1024;
    int v[4]; int s = 0;
    #pragma unroll
    for (int i = 0; i < 4; ++i) {
        int idx = base + t * 4 + i;
        v[i] = (idx < n) ? in[idx] : 0;
        s += v[i];
    }
    lds[t] = s;
    __syncthreads();
    for (int d = 1; d < 256; d <<= 1) {
        int x = (t >= d) ? lds[t - d] : 0;
        __syncthreads();
        lds[t] += x;
        __syncthreads();
    }
    int run = (t > 0) ? lds[t - 1] : 0;
    #pragma unroll
    for (int i = 0; i < 4; ++i) {
        int idx = base + t * 4 + i;
        if (idx < n) out[idx] = run;
        run += v[i];
    }
    if (t == 255) bsums[blockIdx.x] = lds[255];
}

__global__ __launch_bounds__(64) void scan_totals(int* __restrict__ bsums, int nb) {
    int t = threadIdx.x;
    int v = (t < nb) ? bsums[t] : 0;
    #pragma unroll
    for (int d = 1; d < 64; d <<= 1) {
        int u = __shfl_up(v, d, 64);
        if (t >= d) v += u;
    }
    int excl = __shfl_up(v, 1, 64);
    if (t == 0) excl = 0;
    if (t < nb) bsums[t] = excl;
}

__global__ __launch_bounds__(256) void scan_add(int* __restrict__ starts,
                                                int* __restrict__ cursor,
                                                const int* __restrict__ bsums, int n) {
    int i = blockIdx.x * 256 + threadIdx.x;
    if (i < n) { int v = starts[i] + bsums[i >> 10]; starts[i] = v; cursor[i] = v; }
}

// scatter: reorder per-sample data into tid-grouped order.
// struct (32B): {ws0,ws1,ws2,wl0} {wl1,wl2, bits(idxpack), bits(orig_n)}
__global__ __launch_bounds__(256) void scatter_samples(
    const int*   __restrict__ tenso_id,
    const int*   __restrict__ gis, const int* __restrict__ gil,
    const float* __restrict__ gws, const float* __restrict__ gwl,
    int* __restrict__ cursor,
    float4* __restrict__ sdata)
{
    int n = blockIdx.x * 256 + threadIdx.x;
    if (n >= N_SAMP) return;
    int tid = tenso_id[n];
    int pos = atomicAdd(&cursor[tid], 1);
    unsigned bits = (unsigned)gis[n*3+0] | ((unsigned)gis[n*3+1] << 3) | ((unsigned)gis[n*3+2] << 6)
                  | ((unsigned)gil[n*3+0] << 9) | ((unsigned)gil[n*3+1] << 12) | ((unsigned)gil[n*3+2] << 15);
    float4 A = make_float4(gws[n*3+0], gws[n*3+1], gws[n*3+2], gwl[n*3+0]);
    float4 B = make_float4(gwl[n*3+1], gwl[n*3+2], __uint_as_float(bits), __uint_as_float((unsigned)n));
    sdata[(size_t)pos * 2 + 0] = A;
    sdata[(size_t)pos * 2 + 1] = B;
}

// ---------------------------------------------------------------------------
// Gather phase: one wave per tensoRF id. Lanes = 16 samples x 4 channel-
// groups (lane j owns channels 4j..4j+3). Slab rows stride 20 floats ->
// 16B-aligned ds_read_b128 per tap, banks rotate by 20 per row.
// Per 16 samples: 6 b128 tap reads + 8 shuffles (vs 88 DS ops in R4).
// ---------------------------------------------------------------------------
#define ROW_STRIDE 20                 // 16 ch + 4 pad floats
#define TV_F   (24 * ROW_STRIDE)      // 480 floats (3 axes * 8 idx rows)
#define SLAB_F (TV_F + 16 + 48)       // + densities(16) + colors(3,16)
__global__ __launch_bounds__(256) void gather_phase(
    const float* __restrict__ trivecs,   // (P,16,3,8)
    const float* __restrict__ densities, // (P,16)
    const float* __restrict__ colors,    // (P,16,3)
    const int*   __restrict__ starts,
    const int*   __restrict__ counts,
    const float4* __restrict__ sdata,
    float* __restrict__ results_f)       // 1M x 4 floats (lt, r, g, b)
{
    __shared__ __align__(16) float lds[4 * SLAB_F];
    const int lane = threadIdx.x & 63;
    const int wv   = threadIdx.x >> 6;
    const int t    = blockIdx.x * 4 + wv;
    if (t >= P_TENSO) return;

    const int start = starts[t];
    const int cnt   = counts[t];
    if (cnt == 0) return;

    float* slab = lds + wv * SLAB_F;
    float* dl   = slab + TV_F;          // 16 densities
    float* cl   = dl + 16;              // colors (3,16)

    // stage trivec slab: input l = c*24 + (a*8+d)  ->  slab[(a*8+d)*20 + c]
    const float* tvg = trivecs + (size_t)t * 384;
    #pragma unroll
    for (int i = 0; i < 6; ++i) {
        int l = lane + i * 64;
        int c = l / 24;
        int rem = l - c * 24;           // a*8 + d
        slab[rem * ROW_STRIDE + c] = tvg[l];
    }
    if (lane < 16) dl[lane] = densities[(size_t)t * 16 + lane];
    if (lane < 48) {
        int c = lane / 3, k = lane - c * 3;
        cl[k * 16 + c] = colors[(size_t)t * 48 + lane];
    }
    // same-wave LDS write->read dep: compiler inserts lgkmcnt waits

    const int g = lane >> 2;   // sample slot 0..15
    const int j = lane & 3;    // channel group (channels 4j..4j+3)

    const float4 dens4 = *(const float4*)(dl + 4 * j);
    const float4 col0  = *(const float4*)(cl + 4 * j);
    const float4 col1  = *(const float4*)(cl + 16 + 4 * j);
    const float4 col2  = *(const float4*)(cl + 32 + 4 * j);

    const int end = start + cnt;
    const int niter = (cnt + 15) >> 4;

    for (int it = 0; it < niter; ++it) {
        const int pos = start + it * 16 + g;
        const bool valid = (pos < end);
        const int cp = valid ? pos : (end - 1);
        const float4 A = sdata[(size_t)cp * 2 + 0];
        const float4 B = sdata[(size_t)cp * 2 + 1];
        const unsigned bits = __float_as_uint(B.z);
        const unsigned orig = __float_as_uint(B.w);

        float4 f;
        {
            const int is = bits & 7, il = (bits >> 9) & 7;
            const float4 vs = *(const float4*)(slab + is * ROW_STRIDE + 4 * j);
            const float4 vl = *(const float4*)(slab + il * ROW_STRIDE + 4 * j);
            f.x = vs.x * A.x + vl.x * A.w;
            f.y = vs.y * A.x + vl.y * A.w;
            f.z = vs.z * A.x + vl.z * A.w;
            f.w = vs.w * A.x + vl.w * A.w;
        }
        {
            const int is = (bits >> 3) & 7, il = (bits >> 12) & 7;
            const float4 vs = *(const float4*)(slab + 8 * ROW_STRIDE + is * ROW_STRIDE + 4 * j);
            const float4 vl = *(const float4*)(slab + 8 * ROW_STRIDE + il * ROW_STRIDE + 4 * j);
            f.x *= vs.x * A.y + vl.x * B.x;
            f.y *= vs.y * A.y + vl.y * B.x;
            f.z *= vs.z * A.y + vl.z * B.x;
            f.w *= vs.w * A.y + vl.w * B.x;
        }
        {
            const int is = (bits >> 6) & 7, il = (bits >> 15) & 7;
            const float4 vs = *(const float4*)(slab + 16 * ROW_STRIDE + is * ROW_STRIDE + 4 * j);
            const float4 vl = *(const float4*)(slab + 16 * ROW_STRIDE + il * ROW_STRIDE + 4 * j);
            f.x *= vs.x * A.z + vl.x * B.y;
            f.y *= vs.y * A.z + vl.y * B.y;
            f.z *= vs.z * A.z + vl.z * B.y;
            f.w *= vs.w * A.z + vl.w * B.y;
        }

        // per-lane partial sums over its 4 channels
        float s0 = f.x * dens4.x + f.y * dens4.y + f.z * dens4.z + f.w * dens4.w;
        float s1 = f.x * col0.x  + f.y * col0.y  + f.z * col0.z  + f.w * col0.w;
        float s2 = f.x * col1.x  + f.y * col1.y  + f.z * col1.z  + f.w * col1.w;
        float s3 = f.x * col2.x  + f.y * col2.y  + f.z * col2.z  + f.w * col2.w;

        // reduce over the 4 lanes of the quad (masks 1,2)
        s0 += __shfl_xor(s0, 1); s0 += __shfl_xor(s0, 2);
        s1 += __shfl_xor(s1, 1); s1 += __shfl_xor(s1, 2);
        s2 += __shfl_xor(s2, 1); s2 += __shfl_xor(s2, 2);
        s3 += __shfl_xor(s3, 1); s3 += __shfl_xor(s3, 2);

        // lane j emits output component j
        const float sj = (j == 0) ? s0 : (j == 1) ? s1 : (j == 2) ? s2 : s3;
        float val;
        if (j == 0) {
            float dens = fmaxf(sj, 0.0f) + __logf(1.0f + __expf(-fabsf(sj)));
            val = -(dens * DENS_SCALE) * STEP_SZ;            // lt
        } else {
            val = 1.0f / (1.0f + __expf(-sj));               // sigmoid
        }
        if (valid) results_f[(size_t)orig * 4 + j] = val;
    }
}

// ---------------------------------------------------------------------------
// Final pass: one thread per ray (avg 10 samples), sequential recurrence.
// ---------------------------------------------------------------------------
__global__ __launch_bounds__(256) void ray_render(
    const float4* __restrict__ results,
    const float*  __restrict__ t_min,
    const float*  __restrict__ bg,
    const int*    __restrict__ ray_start,
    const int*    __restrict__ step_id,
    float* __restrict__ out)
{
    int r = blockIdx.x * 256 + threadIdx.x;
    if (r >= N_RAYS) return;
    const int s = ray_start[r];
    const int e = ray_start[r + 1];
    const float tmin_r = t_min[r];

    float T = 0.0f, aR = 0.0f, aG = 0.0f, aB = 0.0f, aD = 0.0f;
    for (int n = s; n < e; ++n) {
        float4 res = results[n];
        const float lt = res.x;
        const float w = (1.0f - __expf(lt)) * __expf(T);
        T += lt;
        const float z = tmin_r + (float)step_id[n] * STEP_SZ;
        aR += w * res.y;
        aG += w * res.z;
        aB += w * res.w;
        aD += w * z;
    }
    const float bgw = __expf(T);
    out[0 * N_RAYS + r] = aR + bgw * bg[0];
    out[1 * N_RAYS + r] = aG + bgw * bg[1];
    out[2 * N_RAYS + r] = aB + bgw * bg[2];
    out[3 * N_RAYS + r] = aD;
    out[4 * N_RAYS + r] = 1.0f - bgw;
}

// ---------------------------------------------------------------------------
// Fallback (ws too small): single fused kernel, original layouts.
// ---------------------------------------------------------------------------
__global__ __launch_bounds__(256) void trivec_render_fallback(
    const float* __restrict__ trivecs, const float* __restrict__ densities,
    const float* __restrict__ colors, const float* __restrict__ gws,
    const float* __restrict__ gwl, const float* __restrict__ t_min,
    const float* __restrict__ bg, const int* __restrict__ gis,
    const int* __restrict__ gil, const int* __restrict__ tenso_id,
    const int* __restrict__ ray_id, const int* __restrict__ step_id,
    float* __restrict__ out)
{
    const int lane = threadIdx.x & 63;
    const int r = blockIdx.x * 4 + (threadIdx.x >> 6);
    if (r >= N_RAYS) return;
    const int c = lane & 15;
    const int g = lane >> 4;
    int lo = 0, hi = N_SAMP;
    while (lo < hi) { int mid = (lo + hi) >> 1; if (ray_id[mid] < r) lo = mid + 1; else hi = mid; }
    const int seg_start = lo;
    hi = N_SAMP;
    while (lo < hi) { int mid = (lo + hi) >> 1; if (ray_id[mid] < r + 1) lo = mid + 1; else hi = mid; }
    const int seg_end = lo;
    const float tmin_r = t_min[r];
    float Tlog = 0.0f, accR = 0.0f, accG = 0.0f, accB = 0.0f, accD = 0.0f;
    const int niter = (seg_end - seg_start + 3) >> 2;
    for (int it = 0; it < niter; ++it) {
        const int n = seg_start + it * 4 + g;
        const bool valid = (n < seg_end);
        const int nc = valid ? n : (seg_end - 1);
        const int tid = tenso_id[nc];
        const float* tv = trivecs + (size_t)tid * 384 + c * 24;
        float f = 1.0f;
        #pragma unroll
        for (int a = 0; a < 3; ++a) {
            const int is = gis[nc*3+a], il = gil[nc*3+a];
            const float wS = gws[nc*3+a], wL = gwl[nc*3+a];
            f *= (tv[a*8+is] * wS + tv[a*8+il] * wL);
        }
        const float dns = densities[(size_t)tid * 16 + c];
        const float* colp = colors + ((size_t)tid * 16 + c) * 3;
        float s0 = f*dns, s1 = f*colp[0], s2 = f*colp[1], s3 = f*colp[2];
        #pragma unroll
        for (int m = 1; m < 16; m <<= 1) {
            s0 += __shfl_xor(s0, m); s1 += __shfl_xor(s1, m);
            s2 += __shfl_xor(s2, m); s3 += __shfl_xor(s3, m);
        }
        float dens = fmaxf(s0, 0.0f) + __logf(1.0f + __expf(-fabsf(s0)));
        const float lt = valid ? (-dens * STEP_SZ) : 0.0f;
        const float alpha = 1.0f - __expf(lt);
        const float rr = 1.0f/(1.0f+__expf(-s1)), gg = 1.0f/(1.0f+__expf(-s2)), bb = 1.0f/(1.0f+__expf(-s3));
        const float z = tmin_r + (float)step_id[nc] * STEP_SZ;
        const float lt0 = __shfl(lt,0), lt1 = __shfl(lt,16), lt2 = __shfl(lt,32), lt3 = __shfl(lt,48);
        float excl = Tlog;
        if (g > 0) excl += lt0;
        if (g > 1) excl += lt1;
        if (g > 2) excl += lt2;
        const float w = alpha * __expf(excl);
        Tlog += lt0 + lt1 + lt2 + lt3;
        accR += w*rr; accG += w*gg; accB += w*bb; accD += w*z;
    }
    accR += __shfl_xor(accR,16); accR += __shfl_xor(accR,32);
    accG += __shfl_xor(accG,16); accG += __shfl_xor(accG,32);
    accB += __shfl_xor(accB,16); accB += __shfl_xor(accB,32);
    accD += __shfl_xor(accD,16); accD += __shfl_xor(accD,32);
    const float bgw = __expf(Tlog);
    if (lane == 0) {
        out[0*N_RAYS+r] = accR + bgw*bg[0];
        out[1*N_RAYS+r] = accG + bgw*bg[1];
        out[2*N_RAYS+r] = accB + bgw*bg[2];
        out[3*N_RAYS+r] = accD;
        out[4*N_RAYS+r] = 1.0f - bgw;
    }
}

extern "C" void kernel_launch(void* const* d_in, const int* in_sizes, int n_in,
                              void* d_out, int out_size, void* d_ws, size_t ws_size,
                              hipStream_t stream) {
    const float* trivecs   = (const float*)d_in[0];
    const float* densities = (const float*)d_in[1];
    const float* colors    = (const float*)d_in[2];
    const float* gws       = (const float*)d_in[3];
    const float* gwl       = (const float*)d_in[4];
    const float* t_min     = (const float*)d_in[5];
    const float* bg        = (const float*)d_in[6];
    const int*   gis       = (const int*)d_in[7];
    const int*   gil       = (const int*)d_in[8];
    const int*   tenso_id  = (const int*)d_in[9];
    const int*   ray_id    = (const int*)d_in[10];
    const int*   step_id   = (const int*)d_in[11];
    float* out = (float*)d_out;

    if (ws_size < (size_t)WS_NEED) {
        trivec_render_fallback<<<(N_RAYS + 3) / 4, 256, 0, stream>>>(
            trivecs, densities, colors, gws, gwl, t_min, bg,
            gis, gil, tenso_id, ray_id, step_id, out);
        return;
    }

    char* ws = (char*)d_ws;
    float4* sdata    = (float4*)(ws + OFF_SDATA);
    float4* results  = (float4*)(ws + OFF_RESULTS);
    int*    counts   = (int*)(ws + OFF_COUNTS);
    int*    starts   = (int*)(ws + OFF_STARTS);
    int*    cursor   = (int*)(ws + OFF_CURSOR);
    int*    bsums    = (int*)(ws + OFF_BSUMS);
    int*    raystart = (int*)(ws + OFF_RSTART);

    const int NB = (P_TENSO + 1023) / 1024;   // 49

    zero_ints<<<(P_TENSO + 255) / 256, 256, 0, stream>>>(counts, P_TENSO);
    hist_and_bounds<<<(N_SAMP + 255) / 256, 256, 0, stream>>>(tenso_id, ray_id, counts, raystart);
    scan_local<<<NB, 256, 0, stream>>>(counts, starts, bsums, P_TENSO);
    scan_totals<<<1, 64, 0, stream>>>(bsums, NB);
    scan_add<<<(P_TENSO + 255) / 256, 256, 0, stream>>>(starts, cursor, bsums, P_TENSO);
    scatter_samples<<<(N_SAMP + 255) / 256, 256, 0, stream>>>(
        tenso_id, gis, gil, gws, gwl, cursor, sdata);
    gather_phase<<<(P_TENSO + 3) / 4, 256, 0, stream>>>(
        trivecs, densities, colors, starts, counts, sdata, (float*)results);
    ray_render<<<(N_RAYS + 255) / 256, 256, 0, stream>>>(
        results, t_min, bg, raystart, step_id, out);
}